// Round 1
// baseline (3704.747 us; speedup 1.0000x reference)
//
#include <hip/hip_runtime.h>
#include <cstdint>
#include <cstddef>

#define T_STEPS 512
#define BATCH   64
#define IN_DIM  512
#define HID     768
#define G4H     3072
#define NROWS   32768        // T*B
// h exchange geometry (fp16 plane, MFMA-A fragment-linear: [kb 0..23][kq 0..3][m 0..31][j 0..7])
#define HPLANE  49152        // bytes per group plane (24*4*32*8 elems * 2B)
#define HHALF   24576        // bytes per half-plane (kb 0..11)
#define DBUFB   98304        // bytes per double-buffer slot (2 groups)

typedef __attribute__((ext_vector_type(8))) _Float16 f16x8;
typedef __attribute__((ext_vector_type(4))) float f32x4;

__device__ __forceinline__ float sigmoidf_(float z){ return 1.0f/(1.0f+expf(-z)); }
__device__ __forceinline__ unsigned short f16_bits(float v){
    return __builtin_bit_cast(unsigned short, (_Float16)v);
}

// ---------------- phase 1a: fp32 -> fp16 ----------------
__global__ void cvt_f16_kernel(const float* __restrict__ in, _Float16* __restrict__ out, int n){
    int i = blockIdx.x*256 + threadIdx.x;
    if (i < n) out[i] = (_Float16)in[i];
}

// ---------------- phase 1b: xpT[col][trow] = (x @ W^T)^T, fp16 ----------------
// A = xf16 [32768 x 512], B = wf16 [3072 x 512]. Transposed store: owner lanes in
// the scan read 32 consecutive trows per gate-col (coalesced 2B loads).
__global__ __launch_bounds__(256, 4) void xproj_gemm_t(
    const _Float16* __restrict__ A, const _Float16* __restrict__ B,
    unsigned short* __restrict__ CT)
{
    const int wave = threadIdx.x >> 6;
    const int lane = threadIdx.x & 63;
    const int tile = blockIdx.x*4 + wave;         // 24576 = 512 x 48
    const int mt = tile & 511;
    const int nt = tile >> 9;
    const long m0 = (long)mt*64, n0 = (long)nt*64;
    const int lr = lane & 15, lq = lane >> 4;

    f32x4 acc[4][4];
    #pragma unroll
    for (int i=0;i<4;i++)
        #pragma unroll
        for (int j=0;j<4;j++) acc[i][j] = (f32x4){0.f,0.f,0.f,0.f};

    const _Float16* Ap = A + (m0 + lr)*512 + lq*8;
    const _Float16* Bp = B + (n0 + lr)*512 + lq*8;

    for (int k0 = 0; k0 < 512; k0 += 32){
        f16x8 a[4], b[4];
        #pragma unroll
        for (int i=0;i<4;i++) a[i] = *(const f16x8*)(Ap + (long)i*16*512 + k0);
        #pragma unroll
        for (int j=0;j<4;j++) b[j] = *(const f16x8*)(Bp + (long)j*16*512 + k0);
        #pragma unroll
        for (int i=0;i<4;i++)
            #pragma unroll
            for (int j=0;j<4;j++)
                acc[i][j] = __builtin_amdgcn_mfma_f32_16x16x32_f16(a[i], b[j], acc[i][j], 0,0,0);
    }

    // C row=(lane>>4)*4+reg (M), col=lane&15 (N).
    #pragma unroll
    for (int i=0;i<4;i++)
        #pragma unroll
        for (int j=0;j<4;j++){
            long col = n0 + 16*j + lr;
            long rb  = m0 + 16*i + lq*4;
            unsigned long long pk =
                  (unsigned long long)f16_bits(acc[i][j][0])
                | ((unsigned long long)f16_bits(acc[i][j][1]) << 16)
                | ((unsigned long long)f16_bits(acc[i][j][2]) << 32)
                | ((unsigned long long)f16_bits(acc[i][j][3]) << 48);
            *(unsigned long long*)(CT + col*NROWS + rb) = pk;
        }
}

// ---------------- phase 2: persistent scan, fp16 single-plane ----------------
// 64 blocks x 512 threads (8 waves). bg=bx&1: batch half (32 rows); cb=bx>>1
// owns 24 h-cols (96 gate-cols = 6 N-tiles, zero padding).
// Waves: ks2=w&1 (K-split), mt=(w>>1)&1 (M-tile), ntg=w>>2 (3 N-tiles each).
// U slice: fp16 B-fragments (36 x f16x8 = 144 VGPRs) held for all 512 steps.
// h exchange: uncached (sc0 sc1) loads/stores of a fragment-linear fp16 plane.
__global__ __launch_bounds__(512, 2) void lstm_scan4(
    const float* __restrict__ U,
    const float* __restrict__ bias,
    const float* __restrict__ log_alpha,
    const float* __restrict__ urand,
    const _Float16* __restrict__ xpT,
    float* __restrict__ out,
    char* __restrict__ hbuf,            // 2 dbuf x 2 grp x 49152 B
    unsigned int* __restrict__ bar)
{
    __shared__ _Float16 sH[24576];      // 49152 B: [kb][kq][m 0..31][j 0..7]
    __shared__ float sRed[96*33 + 4];   // gate preacts [c][row], stride 33

    const int tid = threadIdx.x;
    const int bx  = blockIdx.x;
    const int bg  = bx & 1;
    const int cb  = bx >> 1;             // 0..31
    const int hc0 = 24*cb;
    const int row0 = 32*bg;

    const int w    = tid >> 6;
    const int lane = tid & 63;
    const int ks2  = w & 1;
    const int mt   = (w >> 1) & 1;
    const int ntg  = w >> 2;             // 0..1
    const int lr   = lane & 15;
    const int kq   = lane >> 4;
    const int mrow = mt*16 + lr;

    // ---- B fragments (U slice) -> VGPRs, fp16, once ----
    // Bf[q*12+i]: q = N-tile within wave (cols (ntg*3+q)*16+lr), i = kb slot.
    f16x8 Bf[36];
    #pragma unroll
    for (int q=0;q<3;q++){
        const int c = (ntg*3+q)*16 + lr;     // 0..95, all real
        const int g = c/24, jj = c - 24*g;   // gate, h-col-within-block
        const float* up = U + (size_t)(g*HID + hc0 + jj)*HID + kq*8;
        #pragma unroll
        for (int i=0;i<12;i++){
            const int kb = (i<6) ? (ks2*6 + i) : (12 + ks2*6 + (i-6));
            f16x8 v;
            #pragma unroll
            for (int e=0;e<8;e++) v[e] = (_Float16)up[kb*32 + e];
            Bf[q*12+i] = v;
        }
    }

    // ---- per-owner persistent state: oidx = tid (all) and tid+512 (tid<256) ----
    float c_state[2] = {0.f, 0.f};
    float s_cur[2]   = {0.f, 0.f};
    float bgt[2][4]  = {{0.f,0.f,0.f,0.f},{0.f,0.f,0.f,0.f}};
    float la_[2]     = {0.f, 0.f};
    #pragma unroll
    for (int s2=0;s2<2;s2++){
        const int oidx = tid + s2*512;
        if (oidx < 768){
            const int oj  = oidx >> 5;
            const int ohc = hc0 + oj;
            bgt[s2][0] = bias[ohc];
            bgt[s2][1] = bias[HID + ohc];
            bgt[s2][2] = bias[2*HID + ohc];
            bgt[s2][3] = bias[3*HID + ohc];
            la_[s2] = log_alpha[ohc];
            float uu = urand[ohc];
            float lg = (logf(uu) - log1pf(-uu) + la_[s2])*1.5f;
            s_cur[s2] = fminf(fmaxf(1.2f*sigmoidf_(lg) - 0.1f, 0.f), 1.f);
        }
    }
    __syncthreads();

#define ISSUE(ri, ii) do{ \
        const char* p_ = gsrc + (size_t)(tid + (ii)*512)*16; \
        asm volatile("global_load_dwordx4 %0, %1, off sc0 sc1" : "=v"(ri) : "v"(p_)); \
    }while(0)
#define DSW(ri, ii) do{ \
        *(f32x4*)((char*)sH + (size_t)(tid + (ii)*512)*16) = ri; \
    }while(0)

    for (int t = 0; t < T_STEPS; ++t){
        const char* gsrc = hbuf + (size_t)(t&1)*DBUFB + (size_t)bg*HPLANE;

        // owner prefetch (cached; latency hidden under staging+MFMA)
        float xv[2][4] = {{0.f,0.f,0.f,0.f},{0.f,0.f,0.f,0.f}};
        float uun[2]   = {0.5f, 0.5f};
        #pragma unroll
        for (int s2=0;s2<2;s2++){
            const int oidx = tid + s2*512;
            if (oidx < 768){
                const int orow = oidx & 31, oj = oidx >> 5, ohc = hc0 + oj;
                const size_t trow = (size_t)t*BATCH + row0 + orow;
                xv[s2][0] = (float)xpT[(size_t)(0*HID+ohc)*NROWS + trow];
                xv[s2][1] = (float)xpT[(size_t)(1*HID+ohc)*NROWS + trow];
                xv[s2][2] = (float)xpT[(size_t)(2*HID+ohc)*NROWS + trow];
                xv[s2][3] = (float)xpT[(size_t)(3*HID+ohc)*NROWS + trow];
                if (t+1 < T_STEPS) uun[s2] = urand[(size_t)(t+1)*HID + ohc];
            }
        }

        f32x4 r0,r1,r2,r3,r4,r5;
        // half0 (kb 0..11): issue, wait, stage; half1 issued now, consumed after E
        ISSUE(r0,0); ISSUE(r1,1); ISSUE(r2,2);
        asm volatile("s_waitcnt vmcnt(0)" : "+v"(r0),"+v"(r1),"+v"(r2) :: "memory");
        DSW(r0,0); DSW(r1,1); DSW(r2,2);
        ISSUE(r3,3); ISSUE(r4,4); ISSUE(r5,5);
        __syncthreads();

        // phase E: kb in [ks2*6, ks2*6+6). 3 independent acc chains (one per N-tile).
        f32x4 acc0 = {0.f,0.f,0.f,0.f};
        f32x4 acc1 = {0.f,0.f,0.f,0.f};
        f32x4 acc2 = {0.f,0.f,0.f,0.f};
        #pragma unroll
        for (int i=0;i<6;i++){
            const int kb = ks2*6 + i;
            f16x8 a = *(const f16x8*)(sH + (size_t)((kb*4 + kq)*32 + mrow)*8);
            acc0 = __builtin_amdgcn_mfma_f32_16x16x32_f16(a, Bf[i],    acc0, 0,0,0);
            acc1 = __builtin_amdgcn_mfma_f32_16x16x32_f16(a, Bf[12+i], acc1, 0,0,0);
            acc2 = __builtin_amdgcn_mfma_f32_16x16x32_f16(a, Bf[24+i], acc2, 0,0,0);
        }
        // stage half1 (disjoint LDS region; no race with half0 readers)
        asm volatile("s_waitcnt vmcnt(0)" : "+v"(r3),"+v"(r4),"+v"(r5) :: "memory");
        DSW(r3,3); DSW(r4,4); DSW(r5,5);
        __syncthreads();

        // phase G: kb in [12+ks2*6, 12+ks2*6+6)
        #pragma unroll
        for (int i=0;i<6;i++){
            const int kb = 12 + ks2*6 + i;
            f16x8 a = *(const f16x8*)(sH + (size_t)((kb*4 + kq)*32 + mrow)*8);
            acc0 = __builtin_amdgcn_mfma_f32_16x16x32_f16(a, Bf[6+i],  acc0, 0,0,0);
            acc1 = __builtin_amdgcn_mfma_f32_16x16x32_f16(a, Bf[18+i], acc1, 0,0,0);
            acc2 = __builtin_amdgcn_mfma_f32_16x16x32_f16(a, Bf[30+i], acc2, 0,0,0);
        }

        // C combine across the 2 K-split waves (two-pass through sRed)
        {
            const int base_r = mt*16 + kq*4;
            if (ks2 == 0){
                *(f32x4*)(sRed + (size_t)((ntg*3+0)*16 + lr)*33 + base_r) = acc0;
                *(f32x4*)(sRed + (size_t)((ntg*3+1)*16 + lr)*33 + base_r) = acc1;
                *(f32x4*)(sRed + (size_t)((ntg*3+2)*16 + lr)*33 + base_r) = acc2;
            }
            __syncthreads();
            if (ks2 == 1){
                float* rp0 = sRed + (size_t)((ntg*3+0)*16 + lr)*33 + base_r;
                float* rp1 = sRed + (size_t)((ntg*3+1)*16 + lr)*33 + base_r;
                float* rp2 = sRed + (size_t)((ntg*3+2)*16 + lr)*33 + base_r;
                f32x4 o0 = *(const f32x4*)rp0; o0 += acc0; *(f32x4*)rp0 = o0;
                f32x4 o1 = *(const f32x4*)rp1; o1 += acc1; *(f32x4*)rp1 = o1;
                f32x4 o2 = *(const f32x4*)rp2; o2 += acc2; *(f32x4*)rp2 = o2;
            }
            __syncthreads();
        }

        // pointwise LSTM update (768 outputs: all threads own 1, waves 0..3 own 2)
        #pragma unroll
        for (int s2=0;s2<2;s2++){
            const int oidx = tid + s2*512;
            if (oidx < 768){
                const int orow = oidx & 31, oj = oidx >> 5, ohc = hc0 + oj;
                float p0 = sRed[(size_t)(0*24+oj)*33 + orow] + xv[s2][0] + bgt[s2][0];
                float p1 = sRed[(size_t)(1*24+oj)*33 + orow] + xv[s2][1] + bgt[s2][1];
                float p2 = sRed[(size_t)(2*24+oj)*33 + orow] + xv[s2][2] + bgt[s2][2];
                float p3 = sRed[(size_t)(3*24+oj)*33 + orow] + xv[s2][3] + bgt[s2][3];
                const float s = s_cur[s2];
                p0 *= s; p1 *= s; p2 *= s; p3 *= s;
                float ig = sigmoidf_(p0)*s;
                float fg = sigmoidf_(p1)*s;
                float cg = tanhf(p2)*s;
                float og = sigmoidf_(p3)*s;
                c_state[s2] = fg*c_state[s2] + ig*cg;
                float h = og*tanhf(c_state[s2]);
                out[((size_t)t*BATCH + row0 + orow)*HID + ohc] = h;
                if (t+1 < T_STEPS){
                    float lg = (logf(uun[s2]) - log1pf(-uun[s2]) + la_[s2])*1.5f;
                    float sn = fminf(fmaxf(1.2f*sigmoidf_(lg) - 0.1f, 0.f), 1.f);
                    float hs = h * sn;
                    unsigned int vh = f16_bits(hs);
                    char* dst = hbuf + (size_t)((t+1)&1)*DBUFB + (size_t)bg*HPLANE;
                    const int eo = (((ohc>>5)*4 + ((ohc>>3)&3))*32 + orow)*8 + (ohc&7);
                    asm volatile("global_store_short %0, %1, off sc0 sc1"
                                 :: "v"(dst + 2*(size_t)eo), "v"(vh) : "memory");
                    s_cur[s2] = sn;
                }
            }
        }

        // grid barrier (32 blocks per group, 4 striped counters, no L2 fences)
        if (t+1 < T_STEPS){
            asm volatile("s_waitcnt vmcnt(0)" ::: "memory");  // h stores at MALL
            __syncthreads();
            if (tid == 0){
                const unsigned cell = (unsigned)((bg*4 + (cb&3))*32);
                __hip_atomic_fetch_add(bar + cell, 1u, __ATOMIC_RELAXED, __HIP_MEMORY_SCOPE_AGENT);
                const unsigned tgt = (unsigned)(t+1)*32u;
                for (;;){
                    unsigned ssum = 0;
                    #pragma unroll
                    for (int c2=0;c2<4;c2++)
                        ssum += __hip_atomic_load(bar + (bg*4+c2)*32, __ATOMIC_RELAXED, __HIP_MEMORY_SCOPE_AGENT);
                    if (ssum >= tgt) break;
                    __builtin_amdgcn_s_sleep(1);
                }
            }
            __syncthreads();
        }
    }
#undef ISSUE
#undef DSW
}

extern "C" void kernel_launch(void* const* d_in, const int* in_sizes, int n_in,
                              void* d_out, int out_size, void* d_ws, size_t ws_size,
                              hipStream_t stream){
    const float* x  = (const float*)d_in[0];
    const float* W  = (const float*)d_in[1];
    const float* U  = (const float*)d_in[2];
    const float* b  = (const float*)d_in[3];
    const float* la = (const float*)d_in[4];
    const float* u  = (const float*)d_in[5];
    float* out = (float*)d_out;

    char* ws = (char*)d_ws;
    char*           hbuf = ws;                                        // 196608 B
    unsigned int*   bar  = (unsigned int*)(ws + 196608);              // 1024 B used
    _Float16*       xf16 = (_Float16*)(ws + 200704);                  // 33554432 B
    _Float16*       wf16 = (_Float16*)(ws + 200704 + 33554432);       // 3145728 B
    unsigned short* xpT  = (unsigned short*)(ws + 36900864);          // 201326592 B
    // total 238227456 B <= previous session's proven 238424064 B footprint

    hipMemsetAsync(d_ws, 0, 200704, stream);   // zero hbuf (h0=0) + barrier

    cvt_f16_kernel<<<65536, 256, 0, stream>>>(x, xf16, NROWS*IN_DIM);
    cvt_f16_kernel<<<6144,  256, 0, stream>>>(W, wf16, G4H*IN_DIM);
    xproj_gemm_t<<<6144, 256, 0, stream>>>(xf16, wf16, xpT);
    lstm_scan4<<<64, 512, 0, stream>>>(U, b, la, u, (const _Float16*)xpT, out, hbuf, bar);
}